// Round 7
// baseline (3587.841 us; speedup 1.0000x reference)
//
#include <hip/hip_runtime.h>

// ---------------------------------------------------------------------------
// 2-layer GRU, B=64 S=2048 IN=208 H=100 OUT=98, fp32.
//   gemm_bias:  xg0 = seq @ w_ih_l0^T + b_ih_l0          (full-GPU GEMM)
//   gru_fused:  128 persistent blocks (64 producer = layer0, 64 consumer).
// R7 = R5's verified 5-wave structure with the register budget fixed:
// __launch_bounds__(320, 1) -> up to 512 VGPRs/wave, so all 52 float4 of
// weights (2 rows x 2 dots x 13) stay register-resident (R5 failed ONLY
// because (320,2) capped at 256 and the allocator reloaded weights from L2).
//   * 5 waves, 2 rows/thread for dot1 AND dot2; one pass of 13 ds_read_b128
//     per wave feeds all 4 accumulator streams -> 65 LDS-read instrs/step
//     (R6: 130), single barrier per step, gate fully in-register.
//   * pair k-split; pair-sum via DPP quad_perm swap (VALU, not LDS);
//     n_j gathered with one bpermute from pairs 20..29.
// Ring/flag protocol identical to verified R3/R5/R6.
// ---------------------------------------------------------------------------

#define GB_BM 64
#define GB_BN 64
#define GB_BK 16

__global__ __launch_bounds__(256)
void gemm_bias(const float* __restrict__ A, const float* __restrict__ W,
               const float* __restrict__ bias, float* __restrict__ C,
               int Sc, long a_bs, long a_ss, long c_bs, long c_ss,
               int N, int K)
{
    __shared__ float As[GB_BK][68];
    __shared__ float Bs[GB_BK][68];
    const int tid = threadIdx.x;
    const int m0 = blockIdx.x * GB_BM;
    const int n0 = blockIdx.y * GB_BN;

    const int lm = tid >> 2;
    const int lk = (tid & 3) << 2;
    const int row = m0 + lm;
    const float* arow = A + (long)(row / Sc) * a_bs + (long)(row % Sc) * a_ss;
    const int wrow = n0 + lm;
    const float* wrp = W + (long)wrow * K;
    const bool wv_ok = (wrow < N);

    const int tx = tid & 15;
    const int ty = tid >> 4;

    float acc[4][4] = {};

    for (int k0 = 0; k0 < K; k0 += GB_BK) {
        float4 av, bv;
        if (k0 + GB_BK <= K) {
            av = *(const float4*)(arow + k0 + lk);
            bv = wv_ok ? *(const float4*)(wrp + k0 + lk) : make_float4(0.f,0.f,0.f,0.f);
        } else {
            av = make_float4(0.f,0.f,0.f,0.f);
            bv = make_float4(0.f,0.f,0.f,0.f);
            const int kb = k0 + lk;
            if (kb + 0 < K) { av.x = arow[kb+0]; if (wv_ok) bv.x = wrp[kb+0]; }
            if (kb + 1 < K) { av.y = arow[kb+1]; if (wv_ok) bv.y = wrp[kb+1]; }
            if (kb + 2 < K) { av.z = arow[kb+2]; if (wv_ok) bv.z = wrp[kb+2]; }
            if (kb + 3 < K) { av.w = arow[kb+3]; if (wv_ok) bv.w = wrp[kb+3]; }
        }
        As[lk+0][lm] = av.x; As[lk+1][lm] = av.y; As[lk+2][lm] = av.z; As[lk+3][lm] = av.w;
        Bs[lk+0][lm] = bv.x; Bs[lk+1][lm] = bv.y; Bs[lk+2][lm] = bv.z; Bs[lk+3][lm] = bv.w;
        __syncthreads();
        #pragma unroll
        for (int kk = 0; kk < GB_BK; kk++) {
            float4 a  = *(const float4*)&As[kk][ty << 2];
            float4 bb = *(const float4*)&Bs[kk][tx << 2];
            float ar[4] = {a.x, a.y, a.z, a.w};
            float br[4] = {bb.x, bb.y, bb.z, bb.w};
            #pragma unroll
            for (int i = 0; i < 4; i++)
                #pragma unroll
                for (int j = 0; j < 4; j++)
                    acc[i][j] += ar[i] * br[j];
        }
        __syncthreads();
    }

    #pragma unroll
    for (int i = 0; i < 4; i++) {
        const int r = m0 + (ty << 2) + i;
        float* crow = C + (long)(r / Sc) * c_bs + (long)(r % Sc) * c_ss;
        #pragma unroll
        for (int j = 0; j < 4; j++) {
            const int col = n0 + (tx << 2) + j;
            if (col < N) crow[col] = acc[i][j] + bias[col];
        }
    }
}

// ---------------------------------------------------------------------------

#define RING_W 256   // ring depth in timesteps (power of 2), per batch
#define KPUB   16    // flag publish / wait granularity (power of 2)

__device__ __forceinline__ float fsig(float x)  { return 1.f / (1.f + __expf(-x)); }
__device__ __forceinline__ float ftanh(float x) { return 1.f - 2.f / (1.f + __expf(2.f * x)); }

__device__ __forceinline__ void bar_lgkm() {
    asm volatile("s_waitcnt lgkmcnt(0)" ::: "memory");
    __builtin_amdgcn_sched_barrier(0);
    __builtin_amdgcn_s_barrier();
}
__device__ __forceinline__ void bar_full() {
    asm volatile("s_waitcnt vmcnt(0) lgkmcnt(0)" ::: "memory");
    __builtin_amdgcn_sched_barrier(0);
    __builtin_amdgcn_s_barrier();
}
__device__ __forceinline__ void wait_ge(int* p, int tgt) {
    int spins = 0;
    while (__hip_atomic_load(p, __ATOMIC_ACQUIRE, __HIP_MEMORY_SCOPE_AGENT) < tgt) {
        __builtin_amdgcn_s_sleep(2);
        if (++spins > (1 << 22)) break;
    }
}
// pair-swap (lane 2k <-> 2k+1) via DPP quad_perm(1,0,3,2): pure VALU
__device__ __forceinline__ float dpp_swap1(float x) {
    int r = __builtin_amdgcn_update_dpp(0, __float_as_int(x), 0xB1, 0xF, 0xF, false);
    return __int_as_float(r);
}

__global__ __launch_bounds__(320, 1)   // 512-reg budget: weights stay resident
void gru_fused(const float* __restrict__ xg0,      // (B,S,300) precomputed
               const float* __restrict__ w_hh0, const float* __restrict__ b_hh0,
               const float* __restrict__ w_ih1, const float* __restrict__ b_ih1,
               const float* __restrict__ w_hh1, const float* __restrict__ b_hh1,
               const float* __restrict__ w_out, const float* __restrict__ b_out,
               const float* __restrict__ h_init, // (2,B,100)
               float* __restrict__ ring,          // (B, RING_W, 300)
               int* prog0, int* cons1,            // 64*32 ints each
               float* __restrict__ out,           // (B,S,98)
               int S)
{
    __shared__ __align__(16) float hs[2][104];    // double-buffered h state

    const int tid   = threadIdx.x;
    const int layer = blockIdx.x >> 6;   // 0 producer / 1 consumer
    const int b     = blockIdx.x & 63;

    const int wv    = tid >> 6;          // wave 0..4
    const int lane  = tid & 63;
    const int p     = lane >> 1;         // pair 0..31
    const int halfd = lane & 1;          // k-half: 0 -> k<48, 1 -> k>=48
    const int jw    = 20 * wv;
    const int pj    = (p < 20) ? p : 19;
    const int j     = jw + pj;           // gate index (valid when p<20), <=99
    const bool gate = (halfd == 0) && (p < 20);

    // dot1 rows: pairs 0..19 -> (r_j, z_j); pairs 20..29 -> (n_{2m}, n_{2m+1})
    int rA1, rB1;
    if (p < 20)      { rA1 = jw + p;              rB1 = 100 + jw + p; }
    else if (p < 30) { rA1 = 200 + jw + 2*(p-20); rB1 = rA1 + 1; }
    else             { rA1 = 0;                   rB1 = 1; }

    // dot2 rows: thread-pair e covers rows e and e+160
    const int e   = wv * 32 + p;                  // 0..159
    const int N2  = layer ? 98 : 300;
    const bool actA2 = (e < N2);
    const bool actB2 = (e + 160 < N2);
    const int r2A = actA2 ? e : 0;
    const int r2B = actB2 ? e + 160 : 0;

    int* myprog = prog0 + b * 32;
    int* mycons = cons1 + b * 32;

    const float* w_hh = layer ? w_hh1 : w_hh0;
    const float* W2   = layer ? w_out : w_ih1;
    const float* bhh  = layer ? b_hh1 : b_hh0;
    const float* b2   = layer ? b_out : b_ih1;

    // --- weights in registers: 4 rows x 13 float4 = 208 VGPR --------------
    float4 wA1[13], wB1[13], wA2[13], wB2[13];
    {
        const float* pa = w_hh + rA1 * 100 + halfd * 48;
        const float* pb = w_hh + rB1 * 100 + halfd * 48;
        const float* qa = W2   + r2A * 100 + halfd * 48;
        const float* qb = W2   + r2B * 100 + halfd * 48;
        #pragma unroll
        for (int i = 0; i < 13; i++) {
            wA1[i] = *(const float4*)(pa + 4 * i);
            wB1[i] = *(const float4*)(pb + 4 * i);
            wA2[i] = *(const float4*)(qa + 4 * i);
            wB2[i] = *(const float4*)(qb + 4 * i);
        }
        if (!halfd) {   // half0 covers k<48 only: zero the overlap f4
            wA1[12] = make_float4(0.f,0.f,0.f,0.f);
            wB1[12] = make_float4(0.f,0.f,0.f,0.f);
            wA2[12] = make_float4(0.f,0.f,0.f,0.f);
            wB2[12] = make_float4(0.f,0.f,0.f,0.f);
        }
    }
    const float bR = bhh[j], bZ = bhh[100 + j], bN = bhh[200 + j];
    const float b2A = b2[r2A], b2B = b2[r2B];

    float hcur = 0.f;
    if (gate) hcur = h_init[layer * 6400 + b * 100 + j];
    if (tid < 100) hs[0][tid] = h_init[layer * 6400 + b * 100 + tid];

    float* ringb     = ring + (size_t)b * RING_W * 300;
    const float* xgb = xg0 + (size_t)b * (size_t)S * 300;
    float* outb      = out + (size_t)b * (size_t)S * 98;

    float xRn = 0.f, xZn = 0.f, xNn = 0.f;   // prefetched gate x for next step

    if (layer == 0) {
        if (gate) {
            xRn = xgb[j]; xZn = xgb[100 + j]; xNn = xgb[200 + j];
        }
    } else {
        if (tid == 0) wait_ge(myprog, (S < KPUB + 1) ? S : (KPUB + 1));
    }
    __syncthreads();
    if (layer == 1 && gate) {
        xRn = ringb[j]; xZn = ringb[100 + j]; xNn = ringb[200 + j];
    }

    const int slb = 40 + (pj & ~1);      // bpermute source lane for n_j

    for (int t = 0; t < S; t++) {
        const int cur = t & 1;
        const int nxt = cur ^ 1;
        const float xR = xRn, xZ = xZn, xN = xNn;

        // prefetch x for step t+1 (loads stay in flight across the barrier)
        if (gate && t + 1 < S) {
            const float* src = (layer == 0)
                ? xgb + (size_t)(t + 1) * 300
                : ringb + (size_t)((t + 1) & (RING_W - 1)) * 300;
            xRn = src[j]; xZn = src[100 + j]; xNn = src[200 + j];
        }

        // ---- one pass over h_{t-1}: 13 LDS reads feed all 4 accumulators -
        const float4* h4p = (const float4*)hs[cur];
        const int base = halfd * 12;
        float a0[4] = {0.f,0.f,0.f,0.f}, a1[4] = {0.f,0.f,0.f,0.f};
        float a2[4] = {0.f,0.f,0.f,0.f}, a3[4] = {0.f,0.f,0.f,0.f};
        #pragma unroll
        for (int i = 0; i < 13; i++) {
            const float4 h4 = h4p[base + i];
            a0[0] += wA1[i].x * h4.x; a1[0] += wA1[i].y * h4.y;
            a2[0] += wA1[i].z * h4.z; a3[0] += wA1[i].w * h4.w;
            a0[1] += wB1[i].x * h4.x; a1[1] += wB1[i].y * h4.y;
            a2[1] += wB1[i].z * h4.z; a3[1] += wB1[i].w * h4.w;
            a0[2] += wA2[i].x * h4.x; a1[2] += wA2[i].y * h4.y;
            a2[2] += wA2[i].z * h4.z; a3[2] += wA2[i].w * h4.w;
            a0[3] += wB2[i].x * h4.x; a1[3] += wB2[i].y * h4.y;
            a2[3] += wB2[i].z * h4.z; a3[3] += wB2[i].w * h4.w;
        }
        float full[4];
        #pragma unroll
        for (int g = 0; g < 4; g++) {
            const float s = (a0[g] + a2[g]) + (a1[g] + a3[g]);
            full[g] = s + dpp_swap1(s);          // pair-sum: both lanes full
        }

        // n_j lives on pair 20+(j>>1), acc (j&1): one bpermute per acc
        const float nA = __shfl(full[0], slb);
        const float nB = __shfl(full[1], slb);

        if (gate) {
            const float dN = (pj & 1) ? nB : nA;
            const float r = fsig(xR + full[0] + bR);
            const float z = fsig(xZ + full[1] + bZ);
            const float n = ftanh(xN + r * (dN + bN));
            hcur = (1.f - z) * n + z * hcur;
            hs[nxt][j] = hcur;
        }

        // ---- dot2 result for h_{t-1} -> slot/row t-1 ---------------------
        if (t > 0 && halfd == 0) {
            if (layer == 0) {
                float* dst = ringb + (size_t)((t - 1) & (RING_W - 1)) * 300;
                if (actA2) dst[r2A] = full[2] + b2A;
                if (actB2) dst[r2B] = full[3] + b2B;
            } else {
                if (actA2) outb[(size_t)(t - 1) * 98 + r2A] = full[2] + b2A;
            }
        }

        // ---- single barrier + flag protocol ------------------------------
        if (((t + 1) & (KPUB - 1)) == 0) {
            if (layer == 0) {
                bar_full();   // drains ring stores of slots <= t-1
                if (tid == 0) {
                    __hip_atomic_store(myprog, t, __ATOMIC_RELEASE, __HIP_MEMORY_SCOPE_AGENT);
                    const int need = t - 240;         // ring back-pressure
                    if (need > 0) wait_ge(mycons, need);
                }
            } else {
                if (tid == 0) {
                    __hip_atomic_store(mycons, t, __ATOMIC_RELEASE, __HIP_MEMORY_SCOPE_AGENT);
                    int tgt = t + 2 + KPUB;           // covers prefetch <= slot t+1+KPUB
                    if (tgt > S) tgt = S;
                    wait_ge(myprog, tgt);             // BEFORE barrier
                }
                bar_lgkm();
            }
        } else {
            bar_lgkm();
        }
    }

    // ---- final dot2 for h_{S-1} (in hs[S&1]) -----------------------------
    {
        const float4* h4p = (const float4*)hs[S & 1];
        const int base = halfd * 12;
        float c0A = 0.f, c1A = 0.f, c2A = 0.f, c3A = 0.f;
        float c0B = 0.f, c1B = 0.f, c2B = 0.f, c3B = 0.f;
        #pragma unroll
        for (int i = 0; i < 13; i++) {
            const float4 h4 = h4p[base + i];
            c0A += wA2[i].x * h4.x; c1A += wA2[i].y * h4.y;
            c2A += wA2[i].z * h4.z; c3A += wA2[i].w * h4.w;
            c0B += wB2[i].x * h4.x; c1B += wB2[i].y * h4.y;
            c2B += wB2[i].z * h4.z; c3B += wB2[i].w * h4.w;
        }
        float sA = (c0A + c2A) + (c1A + c3A); sA += dpp_swap1(sA);
        float sB = (c0B + c2B) + (c1B + c3B); sB += dpp_swap1(sB);
        if (halfd == 0) {
            if (layer == 0) {
                float* dst = ringb + (size_t)((S - 1) & (RING_W - 1)) * 300;
                if (actA2) dst[r2A] = sA + b2A;
                if (actB2) dst[r2B] = sB + b2B;
            } else {
                if (actA2) outb[(size_t)(S - 1) * 98 + r2A] = sA + b2A;
            }
        }
    }
    if (layer == 0) {
        bar_full();          // drain slot S-1
        if (tid == 0)
            __hip_atomic_store(myprog, S, __ATOMIC_RELEASE, __HIP_MEMORY_SCOPE_AGENT);
    }
}

// ---------------------------------------------------------------------------

extern "C" void kernel_launch(void* const* d_in, const int* in_sizes, int n_in,
                              void* d_out, int out_size, void* d_ws, size_t ws_size,
                              hipStream_t stream)
{
    const float* seq    = (const float*)d_in[0];
    const float* h0     = (const float*)d_in[1];   // (2, 64, 100)
    const float* w_ih0  = (const float*)d_in[2];   // (300, 208)
    const float* w_hh0  = (const float*)d_in[3];   // (300, 100)
    const float* b_ih0  = (const float*)d_in[4];
    const float* b_hh0  = (const float*)d_in[5];
    const float* w_ih1  = (const float*)d_in[6];   // (300, 100)
    const float* w_hh1  = (const float*)d_in[7];
    const float* b_ih1  = (const float*)d_in[8];
    const float* b_hh1  = (const float*)d_in[9];
    const float* w_out  = (const float*)d_in[10];  // (98, 100)
    const float* b_out  = (const float*)d_in[11];
    float* out = (float*)d_out;

    const int B = 64, S = 2048, IN = 208, G = 300;

    // workspace: flags (2 * 64*32 ints) | xg0 (B,S,300) | ring (B,RING_W,300)
    int* prog0 = (int*)d_ws;
    int* cons1 = prog0 + 64 * 32;
    float* xg0 = (float*)(cons1 + 64 * 32);
    float* ringbuf = xg0 + (size_t)B * S * G;

    hipMemsetAsync(d_ws, 0, 2 * 64 * 32 * sizeof(int), stream);

    // xg0 = seq @ w_ih0^T + b_ih0   (full S in one pass)
    const dim3 blk(256);
    const dim3 gX((B * S) / GB_BM, (G + GB_BN - 1) / GB_BN);   // (2048, 5)
    gemm_bias<<<gX, blk, 0, stream>>>(seq, w_ih0, b_ih0, xg0,
                                      S, (long)S * IN, (long)IN,
                                      (long)S * G, (long)G, G, IN);

    // fused persistent 2-layer scan + projections
    gru_fused<<<dim3(128), dim3(320), 0, stream>>>(
        xg0, w_hh0, b_hh0, w_ih1, b_ih1, w_hh1, b_hh1, w_out, b_out,
        h0, ringbuf, prog0, cons1, out, S);
}

// Round 10
// 3069.843 us; speedup vs baseline: 1.1687x; 1.1687x over previous
//
#include <hip/hip_runtime.h>

// ---------------------------------------------------------------------------
// 2-layer GRU, B=64 S=2048 IN=208 H=100 OUT=98, fp32.
//   gemm_bias:  xg0 = seq @ w_ih_l0^T + b_ih_l0          (full-GPU GEMM)
//   gru_fused:  128 persistent blocks (64 producer = layer0, 64 consumer).
// R10 = R9 resubmitted verbatim (R9 hit "container failed twice" with no
// compile/test output -- same infra-flake signature as R2; kernel audited
// for hangs (spins bounded), OOB (all gated), protocol deadlock (none)).
//   * 640 threads = 160 quad-slots. Lane q of a slot covers h elems
//     28q..28q+27 (7 float4). Weights: 4 rows x 7 f4 = 28 f4/thread
//     (<= the empirically AGPR-safe ~26-28; R5/R7 proved 52 f4 reloads).
//   * slot s<100: rows {s, 100+s, 200+s, dot2 row s} -> gate rows co-located
//     in the quad; 2-step quad_perm DPP butterfly (VALU); lane0 computes the
//     gate fully in-register -> hs[nxt][s]. Single barrier per step.
//   * slots 100..149 (layer0): dot2 rows 100+4*(s-100)..+3. Others idle.
//   * LDS instrs/step ~77 (R6: ~190): one h-pass feeds all 4 rows.
// Ring/flag protocol byte-identical to verified R3/R5/R6/R7.
// ---------------------------------------------------------------------------

#define GB_BM 64
#define GB_BN 64
#define GB_BK 16

__global__ __launch_bounds__(256)
void gemm_bias(const float* __restrict__ A, const float* __restrict__ W,
               const float* __restrict__ bias, float* __restrict__ C,
               int Sc, long a_bs, long a_ss, long c_bs, long c_ss,
               int N, int K)
{
    __shared__ float As[GB_BK][68];
    __shared__ float Bs[GB_BK][68];
    const int tid = threadIdx.x;
    const int m0 = blockIdx.x * GB_BM;
    const int n0 = blockIdx.y * GB_BN;

    const int lm = tid >> 2;
    const int lk = (tid & 3) << 2;
    const int row = m0 + lm;
    const float* arow = A + (long)(row / Sc) * a_bs + (long)(row % Sc) * a_ss;
    const int wrow = n0 + lm;
    const float* wrp = W + (long)wrow * K;
    const bool wv_ok = (wrow < N);

    const int tx = tid & 15;
    const int ty = tid >> 4;

    float acc[4][4] = {};

    for (int k0 = 0; k0 < K; k0 += GB_BK) {
        float4 av, bv;
        if (k0 + GB_BK <= K) {
            av = *(const float4*)(arow + k0 + lk);
            bv = wv_ok ? *(const float4*)(wrp + k0 + lk) : make_float4(0.f,0.f,0.f,0.f);
        } else {
            av = make_float4(0.f,0.f,0.f,0.f);
            bv = make_float4(0.f,0.f,0.f,0.f);
            const int kb = k0 + lk;
            if (kb + 0 < K) { av.x = arow[kb+0]; if (wv_ok) bv.x = wrp[kb+0]; }
            if (kb + 1 < K) { av.y = arow[kb+1]; if (wv_ok) bv.y = wrp[kb+1]; }
            if (kb + 2 < K) { av.z = arow[kb+2]; if (wv_ok) bv.z = wrp[kb+2]; }
            if (kb + 3 < K) { av.w = arow[kb+3]; if (wv_ok) bv.w = wrp[kb+3]; }
        }
        As[lk+0][lm] = av.x; As[lk+1][lm] = av.y; As[lk+2][lm] = av.z; As[lk+3][lm] = av.w;
        Bs[lk+0][lm] = bv.x; Bs[lk+1][lm] = bv.y; Bs[lk+2][lm] = bv.z; Bs[lk+3][lm] = bv.w;
        __syncthreads();
        #pragma unroll
        for (int kk = 0; kk < GB_BK; kk++) {
            float4 a  = *(const float4*)&As[kk][ty << 2];
            float4 bb = *(const float4*)&Bs[kk][tx << 2];
            float ar[4] = {a.x, a.y, a.z, a.w};
            float br[4] = {bb.x, bb.y, bb.z, bb.w};
            #pragma unroll
            for (int i = 0; i < 4; i++)
                #pragma unroll
                for (int j = 0; j < 4; j++)
                    acc[i][j] += ar[i] * br[j];
        }
        __syncthreads();
    }

    #pragma unroll
    for (int i = 0; i < 4; i++) {
        const int r = m0 + (ty << 2) + i;
        float* crow = C + (long)(r / Sc) * c_bs + (long)(r % Sc) * c_ss;
        #pragma unroll
        for (int j = 0; j < 4; j++) {
            const int col = n0 + (tx << 2) + j;
            if (col < N) crow[col] = acc[i][j] + bias[col];
        }
    }
}

// ---------------------------------------------------------------------------

#define RING_W 256   // ring depth in timesteps (power of 2), per batch
#define KPUB   16    // flag publish / wait granularity (power of 2)

__device__ __forceinline__ float fsig(float x)  { return 1.f / (1.f + __expf(-x)); }
__device__ __forceinline__ float ftanh(float x) { return 1.f - 2.f / (1.f + __expf(2.f * x)); }

__device__ __forceinline__ void bar_lgkm() {
    asm volatile("s_waitcnt lgkmcnt(0)" ::: "memory");
    __builtin_amdgcn_sched_barrier(0);
    __builtin_amdgcn_s_barrier();
}
__device__ __forceinline__ void bar_full() {
    asm volatile("s_waitcnt vmcnt(0) lgkmcnt(0)" ::: "memory");
    __builtin_amdgcn_sched_barrier(0);
    __builtin_amdgcn_s_barrier();
}
__device__ __forceinline__ void wait_ge(int* p, int tgt) {
    int spins = 0;
    while (__hip_atomic_load(p, __ATOMIC_ACQUIRE, __HIP_MEMORY_SCOPE_AGENT) < tgt) {
        __builtin_amdgcn_s_sleep(2);
        if (++spins > (1 << 22)) break;
    }
}
// quad_perm DPP (pure VALU); ctrl must be compile-time constant.
template <int CTRL>
__device__ __forceinline__ float dpp_qp(float x) {
    int r = __builtin_amdgcn_update_dpp(0, __float_as_int(x), CTRL, 0xF, 0xF, false);
    return __int_as_float(r);
}
__device__ __forceinline__ float quad_red(float x) {   // sum over quad, all lanes
    x += dpp_qp<0xB1>(x);    // quad_perm(1,0,3,2): swap ^1
    x += dpp_qp<0x4E>(x);    // quad_perm(2,3,0,1): swap ^2
    return x;
}

__global__ __launch_bounds__(640, 1)
void gru_fused(const float* __restrict__ xg0,      // (B,S,300) precomputed
               const float* __restrict__ w_hh0, const float* __restrict__ b_hh0,
               const float* __restrict__ w_ih1, const float* __restrict__ b_ih1,
               const float* __restrict__ w_hh1, const float* __restrict__ b_hh1,
               const float* __restrict__ w_out, const float* __restrict__ b_out,
               const float* __restrict__ h_init, // (2,B,100)
               float* __restrict__ ring,          // (B, RING_W, 300)
               int* prog0, int* cons1,            // 64*32 ints each
               float* __restrict__ out,           // (B,S,98)
               int S)
{
    __shared__ __align__(16) float hs[2][112];    // double-buffered, zero-padded

    const int tid   = threadIdx.x;
    const int layer = blockIdx.x >> 6;   // 0 producer / 1 consumer
    const int b     = blockIdx.x & 63;

    const int s = tid >> 2;              // slot 0..159
    const int q = tid & 3;               // k-chunk: h elems 28q..28q+27
    const bool gslot = (s < 100);
    const int N2 = layer ? 98 : 300;

    int* myprog = prog0 + b * 32;
    int* mycons = cons1 + b * 32;

    const float* w_hh = layer ? w_hh1 : w_hh0;
    const float* W2   = layer ? w_out : w_ih1;
    const float* bhhp = layer ? b_hh1 : b_hh0;
    const float* b2p  = layer ? b_out : b_ih1;

    // ---- row assignment --------------------------------------------------
    int r0, r1, r2, r3;
    bool act012, act3;
    if (gslot) {
        r0 = s; r1 = 100 + s; r2 = 200 + s; r3 = s;      // r,z,n + dot2 row s
        act012 = true; act3 = (s < N2);
    } else {
        const int rb = 100 + 4 * (s - 100);              // dot2 rows (layer0)
        r0 = rb; r1 = rb + 1; r2 = rb + 2; r3 = rb + 3;
        act012 = act3 = (layer == 0) && (s < 150);
        if (!act012) { r0 = r1 = r2 = r3 = 0; }
    }

    // ---- weights: 4 rows x 7 f4 = 28 f4 ----------------------------------
    float4 w0[7], w1[7], w2[7], w3[7];
    {
        const float* p0 = (gslot ? w_hh + r0 * 100 : W2 + r0 * 100) + 28 * q;
        const float* p1 = (gslot ? w_hh + r1 * 100 : W2 + r1 * 100) + 28 * q;
        const float* p2 = (gslot ? w_hh + r2 * 100 : W2 + r2 * 100) + 28 * q;
        const float* p3 = W2 + r3 * 100 + 28 * q;        // row3 always dot2
        #pragma unroll
        for (int i = 0; i < 7; i++) {
            const bool kv = (28 * q + 4 * i) < 100;      // f4 fully in-range
            const float4 z4 = make_float4(0.f, 0.f, 0.f, 0.f);
            w0[i] = (kv && act012) ? *(const float4*)(p0 + 4 * i) : z4;
            w1[i] = (kv && act012) ? *(const float4*)(p1 + 4 * i) : z4;
            w2[i] = (kv && act012) ? *(const float4*)(p2 + 4 * i) : z4;
            w3[i] = (kv && act3)   ? *(const float4*)(p3 + 4 * i) : z4;
        }
    }
    // biases
    float bR = 0.f, bZ = 0.f, bN = 0.f, b2g = 0.f, b2q = 0.f;
    if (gslot) {
        if (q == 0) { bR = bhhp[s]; bZ = bhhp[100 + s]; bN = bhhp[200 + s]; }
        if (q == 1 && act3) b2g = b2p[s];
    } else if (act012) {
        b2q = b2p[r0 + q];                               // lane q stores row r0+q
    }

    float hcur = 0.f;
    if (gslot && q == 0) hcur = h_init[layer * 6400 + b * 100 + s];
    if (tid < 112) {
        const float v = (tid < 100) ? h_init[layer * 6400 + b * 100 + tid] : 0.f;
        hs[0][tid] = v;
        if (tid >= 100) hs[1][tid] = 0.f;                // pad stays zero
    }

    float* ringb     = ring + (size_t)b * RING_W * 300;
    const float* xgb = xg0 + (size_t)b * (size_t)S * 300;
    float* outb      = out + (size_t)b * (size_t)S * 98;

    float xRn = 0.f, xZn = 0.f, xNn = 0.f;

    if (layer == 0) {
        if (gslot && q == 0) {
            xRn = xgb[s]; xZn = xgb[100 + s]; xNn = xgb[200 + s];
        }
    } else {
        if (tid == 0) wait_ge(myprog, (S < KPUB + 1) ? S : (KPUB + 1));
    }
    __syncthreads();
    if (layer == 1 && gslot && q == 0) {
        xRn = ringb[s]; xZn = ringb[100 + s]; xNn = ringb[200 + s];
    }

    for (int t = 0; t < S; t++) {
        const int cur = t & 1;
        const int nxt = cur ^ 1;
        const float xR = xRn, xZ = xZn, xN = xNn;

        // prefetch x for step t+1 (loads stay in flight across the barrier)
        if (gslot && q == 0 && t + 1 < S) {
            const float* src = (layer == 0)
                ? xgb + (size_t)(t + 1) * 300
                : ringb + (size_t)((t + 1) & (RING_W - 1)) * 300;
            xRn = src[s]; xZn = src[100 + s]; xNn = src[200 + s];
        }

        // ---- one h-pass (7 LDS reads) feeds all 4 rows -------------------
        const float4* hb = (const float4*)hs[cur];
        float4 h4[7];
        #pragma unroll
        for (int i = 0; i < 7; i++) h4[i] = hb[7 * q + i];

        float p00=0.f,p01=0.f,p02=0.f,p03=0.f;
        float p10=0.f,p11=0.f,p12=0.f,p13=0.f;
        float p20=0.f,p21=0.f,p22=0.f,p23=0.f;
        float p30=0.f,p31=0.f,p32=0.f,p33=0.f;
        #pragma unroll
        for (int i = 0; i < 7; i++) {
            const float4 h = h4[i];
            p00 += w0[i].x*h.x; p01 += w0[i].y*h.y; p02 += w0[i].z*h.z; p03 += w0[i].w*h.w;
            p10 += w1[i].x*h.x; p11 += w1[i].y*h.y; p12 += w1[i].z*h.z; p13 += w1[i].w*h.w;
            p20 += w2[i].x*h.x; p21 += w2[i].y*h.y; p22 += w2[i].z*h.z; p23 += w2[i].w*h.w;
            p30 += w3[i].x*h.x; p31 += w3[i].y*h.y; p32 += w3[i].z*h.z; p33 += w3[i].w*h.w;
        }
        const float red0 = quad_red((p00 + p02) + (p01 + p03));
        const float red1 = quad_red((p10 + p12) + (p11 + p13));
        const float red2 = quad_red((p20 + p22) + (p21 + p23));
        const float red3 = quad_red((p30 + p32) + (p31 + p33));

        // ---- gate fully in-register (lane 0 of gate slot) ----------------
        if (gslot && q == 0) {
            const float r = fsig(xR + red0 + bR);
            const float z = fsig(xZ + red1 + bZ);
            const float n = ftanh(xN + r * (red2 + bN));
            hcur = (1.f - z) * n + z * hcur;
            hs[nxt][s] = hcur;
        }

        // ---- dot2(h_{t-1}) -> ring/out slot t-1 --------------------------
        if (t > 0) {
            if (layer == 0) {
                float* dst = ringb + (size_t)((t - 1) & (RING_W - 1)) * 300;
                if (gslot) {
                    if (q == 1 && act3) dst[s] = red3 + b2g;
                } else if (act012) {
                    float v = red0;
                    if (q == 1) v = red1;
                    if (q == 2) v = red2;
                    if (q == 3) v = red3;
                    dst[r0 + q] = v + b2q;
                }
            } else {
                if (gslot && q == 1 && act3)
                    outb[(size_t)(t - 1) * 98 + s] = red3 + b2g;
            }
        }

        // ---- single barrier + flag protocol (verified R5/R7) -------------
        if (((t + 1) & (KPUB - 1)) == 0) {
            if (layer == 0) {
                bar_full();   // drains ring stores of slots <= t-1
                if (tid == 0) {
                    __hip_atomic_store(myprog, t, __ATOMIC_RELEASE, __HIP_MEMORY_SCOPE_AGENT);
                    const int need = t - 240;         // ring back-pressure
                    if (need > 0) wait_ge(mycons, need);
                }
            } else {
                if (tid == 0) {
                    __hip_atomic_store(mycons, t, __ATOMIC_RELEASE, __HIP_MEMORY_SCOPE_AGENT);
                    int tgt = t + 2 + KPUB;           // covers prefetch <= slot t+1+KPUB
                    if (tgt > S) tgt = S;
                    wait_ge(myprog, tgt);             // BEFORE barrier
                }
                bar_lgkm();
            }
        } else {
            bar_lgkm();
        }
    }

    // ---- epilogue: dot2 for h_{S-1} (in hs[S&1]) -> slot/row S-1 ---------
    {
        const float4* hb = (const float4*)hs[S & 1];
        float4 h4[7];
        #pragma unroll
        for (int i = 0; i < 7; i++) h4[i] = hb[7 * q + i];
        float p00=0.f,p01=0.f,p02=0.f,p03=0.f;
        float p10=0.f,p11=0.f,p12=0.f,p13=0.f;
        float p20=0.f,p21=0.f,p22=0.f,p23=0.f;
        float p30=0.f,p31=0.f,p32=0.f,p33=0.f;
        #pragma unroll
        for (int i = 0; i < 7; i++) {
            const float4 h = h4[i];
            p00 += w0[i].x*h.x; p01 += w0[i].y*h.y; p02 += w0[i].z*h.z; p03 += w0[i].w*h.w;
            p10 += w1[i].x*h.x; p11 += w1[i].y*h.y; p12 += w1[i].z*h.z; p13 += w1[i].w*h.w;
            p20 += w2[i].x*h.x; p21 += w2[i].y*h.y; p22 += w2[i].z*h.z; p23 += w2[i].w*h.w;
            p30 += w3[i].x*h.x; p31 += w3[i].y*h.y; p32 += w3[i].z*h.z; p33 += w3[i].w*h.w;
        }
        const float red0 = quad_red((p00 + p02) + (p01 + p03));
        const float red1 = quad_red((p10 + p12) + (p11 + p13));
        const float red2 = quad_red((p20 + p22) + (p21 + p23));
        const float red3 = quad_red((p30 + p32) + (p31 + p33));
        if (layer == 0) {
            float* dst = ringb + (size_t)((S - 1) & (RING_W - 1)) * 300;
            if (gslot) {
                if (q == 1 && act3) dst[s] = red3 + b2g;
            } else if (act012) {
                float v = red0;
                if (q == 1) v = red1;
                if (q == 2) v = red2;
                if (q == 3) v = red3;
                dst[r0 + q] = v + b2q;
            }
        } else {
            if (gslot && q == 1 && act3)
                outb[(size_t)(S - 1) * 98 + s] = red3 + b2g;
        }
    }
    if (layer == 0) {
        bar_full();          // drain slot S-1
        if (tid == 0)
            __hip_atomic_store(myprog, S, __ATOMIC_RELEASE, __HIP_MEMORY_SCOPE_AGENT);
    }
}

// ---------------------------------------------------------------------------

extern "C" void kernel_launch(void* const* d_in, const int* in_sizes, int n_in,
                              void* d_out, int out_size, void* d_ws, size_t ws_size,
                              hipStream_t stream)
{
    const float* seq    = (const float*)d_in[0];
    const float* h0     = (const float*)d_in[1];   // (2, 64, 100)
    const float* w_ih0  = (const float*)d_in[2];   // (300, 208)
    const float* w_hh0  = (const float*)d_in[3];   // (300, 100)
    const float* b_ih0  = (const float*)d_in[4];
    const float* b_hh0  = (const float*)d_in[5];
    const float* w_ih1  = (const float*)d_in[6];   // (300, 100)
    const float* w_hh1  = (const float*)d_in[7];
    const float* b_ih1  = (const float*)d_in[8];
    const float* b_hh1  = (const float*)d_in[9];
    const float* w_out  = (const float*)d_in[10];  // (98, 100)
    const float* b_out  = (const float*)d_in[11];
    float* out = (float*)d_out;

    const int B = 64, S = 2048, IN = 208, G = 300;

    // workspace: flags (2 * 64*32 ints) | xg0 (B,S,300) | ring (B,RING_W,300)
    int* prog0 = (int*)d_ws;
    int* cons1 = prog0 + 64 * 32;
    float* xg0 = (float*)(cons1 + 64 * 32);
    float* ringbuf = xg0 + (size_t)B * S * G;

    (void)hipMemsetAsync(d_ws, 0, 2 * 64 * 32 * sizeof(int), stream);

    // xg0 = seq @ w_ih0^T + b_ih0   (full S in one pass)
    const dim3 blk(256);
    const dim3 gX((B * S) / GB_BM, (G + GB_BN - 1) / GB_BN);   // (2048, 5)
    gemm_bias<<<gX, blk, 0, stream>>>(seq, w_ih0, b_ih0, xg0,
                                      S, (long)S * IN, (long)IN,
                                      (long)S * G, (long)G, G, IN);

    // fused persistent 2-layer scan + projections
    gru_fused<<<dim3(128), dim3(640), 0, stream>>>(
        xg0, w_hh0, b_hh0, w_ih1, b_ih1, w_hh1, b_hh1, w_out, b_out,
        h0, ringbuf, prog0, cons1, out, S);
}